// Round 1
// baseline (686.432 us; speedup 1.0000x reference)
//
#include <hip/hip_runtime.h>

#define LL 784
#define CHI 128
#define CLS 10
#define BC 16
#define NBLK 64          // 1024/16

typedef __attribute__((ext_vector_type(8))) short short8;
typedef __attribute__((ext_vector_type(4))) float floatx4;

__device__ inline unsigned int f2bf(float v) {
    unsigned int u = __float_as_uint(v);
    u += 0x7fffu + ((u >> 16) & 1u);   // RNE
    return u >> 16;
}

// workgroup barrier that does NOT drain vmcnt — keeps W/x prefetch in flight.
__device__ inline void lds_barrier() {
    asm volatile("s_waitcnt lgkmcnt(0)\n\ts_barrier" ::: "memory");
}

// packed fp32x2 -> bf16x2 (RNE), lo = first arg
__device__ inline unsigned int cvt_pk_bf16(float lo, float hi) {
    unsigned int r;
    asm("v_cvt_pk_bf16_f32 %0, %1, %2" : "=v"(r) : "v"(lo), "v"(hi));
    return r;
}

// ---------------------------------------------------------------------------
// prep: W fp32 (L,2,CHI,CHI) -> bf16 MFMA fragments via LDS transpose.
// UNCHANGED from previous version: the same (lane,elem) map serves as the
// A-operand fragment of the transposed compute (A[i=l&15][k=(l>>4)*8+j]).
// ws uint4 index: (((n*8 + nt)*2 + s)*4 + kt)*64 + l
//   lane l elem j: value = W[n][s][a = kt*32 + (l>>4)*8 + j][c = nt*16 + (l&15)]
// ---------------------------------------------------------------------------
__global__ __launch_bounds__(256) void prep_kernel(const float* __restrict__ W,
                                                   uint4* __restrict__ ws4) {
    __shared__ float tile[32 * 132];
    const int b = blockIdx.x;            // n*8 + s*4 + kt
    const int n = b >> 3, s = (b >> 2) & 1, kt = b & 3;
    const float* Wp = W + ((size_t)(n * 2 + s) * CHI + kt * 32) * CHI;
    const int t = threadIdx.x;
    #pragma unroll
    for (int k = 0; k < 4; k++) {
        int v = t + k * 256;             // 0..1023 float4s
        int a = v >> 5, c4 = v & 31;
        float4 val = *(const float4*)(Wp + a * CHI + c4 * 4);
        *(float4*)&tile[a * 132 + c4 * 4] = val;
    }
    __syncthreads();
    const int l = t & 63, f0 = t >> 6;
    const int m_ = l & 15, q_ = l >> 4;
    #pragma unroll
    for (int ff = 0; ff < 2; ff++) {
        int nt = f0 + ff * 4;
        const float* tp = &tile[(q_ * 8) * 132 + nt * 16 + m_];
        uint4 pk;
        pk.x = f2bf(tp[0 * 132]) | (f2bf(tp[1 * 132]) << 16);
        pk.y = f2bf(tp[2 * 132]) | (f2bf(tp[3 * 132]) << 16);
        pk.z = f2bf(tp[4 * 132]) | (f2bf(tp[5 * 132]) << 16);
        pk.w = f2bf(tp[6 * 132]) | (f2bf(tp[7 * 132]) << 16);
        ws4[(size_t)(((n * 8 + nt) * 2 + s) * 4 + kt) * 64 + l] = pk;
    }
}

// ---------------------------------------------------------------------------
// main (TRANSPOSED): 64 blocks x 256 threads (4 waves). Block owns 16 batch
// rows. Compute D[c][b] = sum_a W[a][c] * h[b][a]  (A = W^T frags = ws
// unchanged; B = h^T frags). Lane (m,q) of wave w holds h[b=m][c=w*32+ct*16+
// q*4+i] in fp32 (exact). Next-site B-frag pack: batch is lane-local, the 4
// chi values are consecutive -> 2 x v_cvt_pk_bf16_f32 + 1 ds_write_b64 per
// ct, all lanes, conflict-free. x[b][s] is lane-resident (b=m), prefetched
// from global 8 sites ahead -> zero per-site x LDS traffic.
// Per site per CU: 16 ds_read_b128 + 8 ds_write_b64 (vs 48 reads + 32 writes
// before), one 4-wave barrier. W frags prefetched 2 sites ahead in registers.
// ---------------------------------------------------------------------------
__global__ __launch_bounds__(256, 1) void mps_kernel(const float* __restrict__ x,
                                                     const unsigned short* __restrict__ ws,
                                                     const float* __restrict__ V,
                                                     float* __restrict__ out) {
    __shared__ short8 bfbuf[2][4][64];   // [par][kt][lane] B-frags of h^T, 8 KB
    __shared__ float hfin[BC * 136];     // final h for h@V (stride 136: 16B-aligned rows)

    const int t = threadIdx.x;
    const int w = t >> 6, l = t & 63;
    const int m = l & 15, q = l >> 4;
    const int rb = blockIdx.x * BC;

    // init bfbuf[0] = bf16(1.0)  (1024 uints, 256 threads -> 4 each)
    for (int i = t; i < 1024; i += 256)
        ((unsigned int*)&bfbuf[0][0][0])[i] = 0x3F803F80u;

    // ---- x: per-lane registers, batch row b = m (q-groups redundant) ----
    const float* xp0 = x + (size_t)(rb + m) * (2 * LL);   // s = 0
    const float* xp1 = xp0 + LL;                          // s = 1
    float4 xA0, xA1, xA2, xA3, xB0, xB1, xB2, xB3;
    xA0 = *(const float4*)(xp0 + 0);  xA1 = *(const float4*)(xp0 + 4);
    xA2 = *(const float4*)(xp1 + 0);  xA3 = *(const float4*)(xp1 + 4);

    // ---- W prefetch: wave w owns c-tiles nt = 2w, 2w+1 ----
    // frag (ct,s,kt) at shorts offset n*32768 + w*8192 + (ct*8+s*4+kt)*512 + l*8
    const unsigned short* wsw = ws + (size_t)w * 8192 + (size_t)l * 8;
    short8 bWA[16], bWB[16];
    #pragma unroll
    for (int f = 0; f < 16; f++) {
        bWA[f] = *(const short8*)(wsw + (size_t)0 * 32768 + f * 512);
        bWB[f] = *(const short8*)(wsw + (size_t)1 * 32768 + f * 512);
    }

    floatx4 hacc0 = (floatx4){1.f, 1.f, 1.f, 1.f};   // ct=0: c = w*32 + q*4 + i
    floatx4 hacc1 = (floatx4){1.f, 1.f, 1.f, 1.f};   // ct=1: c = w*32 + 16 + q*4 + i

    // ds_write dword offset (kt = w since c0 = w*32 + [0,28]):
    //   byte = w*1024 + (q>>1)*256 + m*16 + (q&1)*8  (+ ct*512 + par'*4096)
    unsigned int* const bfw = (unsigned int*)&bfbuf[0][0][0];
    const int wr_dw = w * 256 + (q >> 1) * 64 + m * 4 + (q & 1) * 2;

#define SITE_BODY(NN, PAR, WBUF, X0, X1) do {                                       \
    lds_barrier();                                                                  \
    short8 bf0 = bfbuf[PAR][0][l];                                                  \
    short8 bf1 = bfbuf[PAR][1][l];                                                  \
    short8 bf2 = bfbuf[PAR][2][l];                                                  \
    short8 bf3 = bfbuf[PAR][3][l];                                                  \
    floatx4 z = (floatx4){0.f, 0.f, 0.f, 0.f};                                      \
    floatx4 p0l = __builtin_amdgcn_mfma_f32_16x16x32_bf16(WBUF[0],  bf0, z, 0,0,0); \
    floatx4 p0h = __builtin_amdgcn_mfma_f32_16x16x32_bf16(WBUF[2],  bf2, z, 0,0,0); \
    floatx4 p1l = __builtin_amdgcn_mfma_f32_16x16x32_bf16(WBUF[4],  bf0, z, 0,0,0); \
    floatx4 p1h = __builtin_amdgcn_mfma_f32_16x16x32_bf16(WBUF[6],  bf2, z, 0,0,0); \
    floatx4 q0l = __builtin_amdgcn_mfma_f32_16x16x32_bf16(WBUF[8],  bf0, z, 0,0,0); \
    floatx4 q0h = __builtin_amdgcn_mfma_f32_16x16x32_bf16(WBUF[10], bf2, z, 0,0,0); \
    floatx4 q1l = __builtin_amdgcn_mfma_f32_16x16x32_bf16(WBUF[12], bf0, z, 0,0,0); \
    floatx4 q1h = __builtin_amdgcn_mfma_f32_16x16x32_bf16(WBUF[14], bf2, z, 0,0,0); \
    p0l = __builtin_amdgcn_mfma_f32_16x16x32_bf16(WBUF[1],  bf1, p0l, 0,0,0);       \
    p0h = __builtin_amdgcn_mfma_f32_16x16x32_bf16(WBUF[3],  bf3, p0h, 0,0,0);       \
    p1l = __builtin_amdgcn_mfma_f32_16x16x32_bf16(WBUF[5],  bf1, p1l, 0,0,0);       \
    p1h = __builtin_amdgcn_mfma_f32_16x16x32_bf16(WBUF[7],  bf3, p1h, 0,0,0);       \
    q0l = __builtin_amdgcn_mfma_f32_16x16x32_bf16(WBUF[9],  bf1, q0l, 0,0,0);       \
    q0h = __builtin_amdgcn_mfma_f32_16x16x32_bf16(WBUF[11], bf3, q0h, 0,0,0);       \
    q1l = __builtin_amdgcn_mfma_f32_16x16x32_bf16(WBUF[13], bf1, q1l, 0,0,0);       \
    q1h = __builtin_amdgcn_mfma_f32_16x16x32_bf16(WBUF[15], bf3, q1h, 0,0,0);       \
    if ((NN) + 2 < LL) {                                                            \
        _Pragma("unroll")                                                           \
        for (int f = 0; f < 16; f++)                                                \
            WBUF[f] = *(const short8*)(wsw + (size_t)((NN) + 2) * 32768 + f * 512); \
    }                                                                               \
    _Pragma("unroll")                                                               \
    for (int i = 0; i < 4; i++) {                                                   \
        hacc0[i] += (X0) * (p0l[i] + p0h[i]) + (X1) * (p1l[i] + p1h[i]);            \
        hacc1[i] += (X0) * (q0l[i] + q0h[i]) + (X1) * (q1l[i] + q1h[i]);            \
    }                                                                               \
    uint2 pk0, pk1;                                                                 \
    pk0.x = cvt_pk_bf16(hacc0[0], hacc0[1]);                                        \
    pk0.y = cvt_pk_bf16(hacc0[2], hacc0[3]);                                        \
    pk1.x = cvt_pk_bf16(hacc1[0], hacc1[1]);                                        \
    pk1.y = cvt_pk_bf16(hacc1[2], hacc1[3]);                                        \
    *(uint2*)&bfw[((PAR) ^ 1) * 1024 + wr_dw]       = pk0;                          \
    *(uint2*)&bfw[((PAR) ^ 1) * 1024 + 128 + wr_dw] = pk1;                          \
} while (0)

    for (int nb = 0; nb < LL; nb += 16) {
        // prefetch x group (nb+8 .. nb+15) into B buffers (dead since nb-1)
        if (nb + 8 < LL) {
            xB0 = *(const float4*)(xp0 + nb + 8);
            xB1 = *(const float4*)(xp0 + nb + 12);
            xB2 = *(const float4*)(xp1 + nb + 8);
            xB3 = *(const float4*)(xp1 + nb + 12);
        }
        SITE_BODY(nb + 0,  0, bWA, xA0.x, xA2.x);
        SITE_BODY(nb + 1,  1, bWB, xA0.y, xA2.y);
        SITE_BODY(nb + 2,  0, bWA, xA0.z, xA2.z);
        SITE_BODY(nb + 3,  1, bWB, xA0.w, xA2.w);
        SITE_BODY(nb + 4,  0, bWA, xA1.x, xA3.x);
        SITE_BODY(nb + 5,  1, bWB, xA1.y, xA3.y);
        SITE_BODY(nb + 6,  0, bWA, xA1.z, xA3.z);
        SITE_BODY(nb + 7,  1, bWB, xA1.w, xA3.w);
        // prefetch x group (nb+16 .. nb+23) into A buffers (dead since nb+7)
        if (nb + 16 < LL) {
            xA0 = *(const float4*)(xp0 + nb + 16);
            xA1 = *(const float4*)(xp0 + nb + 20);
            xA2 = *(const float4*)(xp1 + nb + 16);
            xA3 = *(const float4*)(xp1 + nb + 20);
        }
        SITE_BODY(nb + 8,  0, bWA, xB0.x, xB2.x);
        SITE_BODY(nb + 9,  1, bWB, xB0.y, xB2.y);
        SITE_BODY(nb + 10, 0, bWA, xB0.z, xB2.z);
        SITE_BODY(nb + 11, 1, bWB, xB0.w, xB2.w);
        SITE_BODY(nb + 12, 0, bWA, xB1.x, xB3.x);
        SITE_BODY(nb + 13, 1, bWB, xB1.y, xB3.y);
        SITE_BODY(nb + 14, 0, bWA, xB1.z, xB3.z);
        SITE_BODY(nb + 15, 1, bWB, xB1.w, xB3.w);
    }
#undef SITE_BODY

    // hacc (exact fp32) -> LDS, then logits = h @ V
    *(floatx4*)&hfin[m * 136 + w * 32 + q * 4]      = hacc0;
    *(floatx4*)&hfin[m * 136 + w * 32 + 16 + q * 4] = hacc1;
    __syncthreads();

    if (t < BC * CLS) {
        int r = t / CLS, cls = t % CLS;
        float sum = 0.f;
        for (int a = 0; a < CHI; a++) sum += hfin[r * 136 + a] * V[a * CLS + cls];
        out[(size_t)(rb + r) * CLS + cls] = sum;
    }
}

extern "C" void kernel_launch(void* const* d_in, const int* in_sizes, int n_in,
                              void* d_out, int out_size, void* d_ws, size_t ws_size,
                              hipStream_t stream) {
    const float* x = (const float*)d_in[0];
    const float* W = (const float*)d_in[1];
    const float* V = (const float*)d_in[2];
    float* out = (float*)d_out;

    prep_kernel<<<LL * 8, 256, 0, stream>>>(W, (uint4*)d_ws);
    mps_kernel<<<NBLK, 256, 0, stream>>>(x, (const unsigned short*)d_ws, V, out);
}

// Round 3
// 684.486 us; speedup vs baseline: 1.0028x; 1.0028x over previous
//
#include <hip/hip_runtime.h>

#define LL 784
#define CHI 128
#define CLS 10
#define BC 16
#define NBLK 64          // 1024/16

typedef __attribute__((ext_vector_type(8))) short short8;
typedef __attribute__((ext_vector_type(4))) float floatx4;

__device__ inline unsigned int f2bf(float v) {
    unsigned int u = __float_as_uint(v);
    u += 0x7fffu + ((u >> 16) & 1u);   // RNE
    return u >> 16;
}

// workgroup barrier that does NOT drain vmcnt — keeps W prefetch in flight.
__device__ inline void lds_barrier() {
    asm volatile("s_waitcnt lgkmcnt(0)\n\ts_barrier" ::: "memory");
}

// packed fp32x2 -> bf16x2 (RNE), lo = first arg
__device__ inline unsigned int cvt_pk_bf16(float lo, float hi) {
    unsigned int r;
    asm("v_cvt_pk_bf16_f32 %0, %1, %2" : "=v"(r) : "v"(lo), "v"(hi));
    return r;
}

// un-sinkable 16B global load: volatile asm pins the ISSUE position so the
// compiler cannot defeat the 2-site software prefetch (round-1 failure mode:
// VGPR_Count=136 proved the compiler sank the C-level prefetch loads).
template <int OFF>
__device__ inline short8 gload(const char* p) {
    short8 r;
    asm volatile("global_load_dwordx4 %0, %1, off offset:%2"
                 : "=v"(r) : "v"(p), "i"(OFF));
    return r;
}

__device__ inline floatx4 gloadf4(const float* p) {
    floatx4 r;
    asm volatile("global_load_dwordx4 %0, %1, off"
                 : "=v"(r) : "v"(p));
    return r;
}

// counted wait: all but the newest 8 vmem ops complete (= this site's W batch
// done, next site's batch stays in flight). sched_barrier stops MFMA hoisting
// above the wait (guide rule #18).
__device__ inline void vm_wait8() {
    asm volatile("s_waitcnt vmcnt(8)" ::: "memory");
    __builtin_amdgcn_sched_barrier(0);
}
__device__ inline void vm_wait0() {
    asm volatile("s_waitcnt vmcnt(0)" ::: "memory");
    __builtin_amdgcn_sched_barrier(0);
}

// ---------------------------------------------------------------------------
// prep: W fp32 (L,2,CHI,CHI) -> bf16 MFMA fragments via LDS transpose.
// UNCHANGED (layout verified by passing rounds).
// ws uint4 index: (((n*8 + nt)*2 + s)*4 + kt)*64 + l
//   lane l elem j: value = W[n][s][a = kt*32 + (l>>4)*8 + j][c = nt*16 + (l&15)]
// ---------------------------------------------------------------------------
__global__ __launch_bounds__(256) void prep_kernel(const float* __restrict__ W,
                                                   uint4* __restrict__ ws4) {
    __shared__ float tile[32 * 132];
    const int b = blockIdx.x;            // n*8 + s*4 + kt
    const int n = b >> 3, s = (b >> 2) & 1, kt = b & 3;
    const float* Wp = W + ((size_t)(n * 2 + s) * CHI + kt * 32) * CHI;
    const int t = threadIdx.x;
    #pragma unroll
    for (int k = 0; k < 4; k++) {
        int v = t + k * 256;             // 0..1023 float4s
        int a = v >> 5, c4 = v & 31;
        float4 val = *(const float4*)(Wp + a * CHI + c4 * 4);
        *(float4*)&tile[a * 132 + c4 * 4] = val;
    }
    __syncthreads();
    const int l = t & 63, f0 = t >> 6;
    const int m_ = l & 15, q_ = l >> 4;
    #pragma unroll
    for (int ff = 0; ff < 2; ff++) {
        int nt = f0 + ff * 4;
        const float* tp = &tile[(q_ * 8) * 132 + nt * 16 + m_];
        uint4 pk;
        pk.x = f2bf(tp[0 * 132]) | (f2bf(tp[1 * 132]) << 16);
        pk.y = f2bf(tp[2 * 132]) | (f2bf(tp[3 * 132]) << 16);
        pk.z = f2bf(tp[4 * 132]) | (f2bf(tp[5 * 132]) << 16);
        pk.w = f2bf(tp[6 * 132]) | (f2bf(tp[7 * 132]) << 16);
        ws4[(size_t)(((n * 8 + nt) * 2 + s) * 4 + kt) * 64 + l] = pk;
    }
}

// ---------------------------------------------------------------------------
// main: 64 blocks x 512 threads (8 waves). Wave w owns c-tile nt=w (16 output
// chi). Transposed compute D[c][b] = sum_a W[a][c] h[b][a]; A-frags = ws
// (unchanged), B-frags = bf16 h in LDS ping-pong (1 lgkm barrier/site).
// W: 8 frags/site/wave, double-buffered in VGPRs, loaded with volatile-asm
// global_load_dwordx4 2 sites ahead; per-site s_waitcnt vmcnt(8) keeps the
// next site's batch permanently in flight. x loads are ALSO volatile-asm
// (zero compiler-emitted vmem in the loop -> no spurious vmcnt(0) drains);
// each x batch is issued >=8 sites before first use, so the per-site
// vmcnt(8) chain already guarantees completion. Last 16 sites peeled with
// literal indices: site 783 drains with vmcnt(0) (its batch is the only one
// outstanding there, so vmcnt(8) would be a no-op -> garbage).
// ---------------------------------------------------------------------------
__global__ __launch_bounds__(512) void mps_kernel(const float* __restrict__ x,
                                                  const unsigned short* __restrict__ ws,
                                                  const float* __restrict__ V,
                                                  float* __restrict__ out) {
    __shared__ short8 bfbuf[2][4][64];   // [par][kt][lane] B-frags of h^T, 8 KB
    __shared__ float hfin[BC * 136];     // final h for h@V

    const int t = threadIdx.x;
    const int w = t >> 6, l = t & 63;
    const int m = l & 15, q = l >> 4;
    const int rb = blockIdx.x * BC;

    // init bfbuf[0] = bf16(1.0)  (1024 uints, 512 threads -> 2 each)
    for (int i = t; i < 1024; i += 512)
        ((unsigned int*)&bfbuf[0][0][0])[i] = 0x3F803F80u;

    // ---- x: per-lane registers, batch row b = m ----
    const float* xp0 = x + (size_t)(rb + m) * (2 * LL);   // s = 0
    const float* xp1 = xp0 + LL;                          // s = 1
    floatx4 xA0, xA1, xA2, xA3, xB0, xB1, xB2, xB3;
    xA0 = gloadf4(xp0 + 0);  xA1 = gloadf4(xp0 + 4);
    xA2 = gloadf4(xp1 + 0);  xA3 = gloadf4(xp1 + 4);

    // ---- W: wave-private byte base; frag f=s*4+kt at +f*1024, site at +n*65536
    const char* wsb = (const char*)ws + (size_t)w * 8192 + (size_t)l * 16;

    short8 bWA[8], bWB[8];
    {
        const char* p0 = wsb;                 // site 0
        const char* p1 = wsb + 65536;         // site 1
        bWA[0] = gload<0>(p0);           bWA[1] = gload<1024>(p0);
        bWA[2] = gload<2048>(p0);        bWA[3] = gload<3072>(p0);
        bWA[4] = gload<0>(p0 + 4096);    bWA[5] = gload<1024>(p0 + 4096);
        bWA[6] = gload<2048>(p0 + 4096); bWA[7] = gload<3072>(p0 + 4096);
        bWB[0] = gload<0>(p1);           bWB[1] = gload<1024>(p1);
        bWB[2] = gload<2048>(p1);        bWB[3] = gload<3072>(p1);
        bWB[4] = gload<0>(p1 + 4096);    bWB[5] = gload<1024>(p1 + 4096);
        bWB[6] = gload<2048>(p1 + 4096); bWB[7] = gload<3072>(p1 + 4096);
    }

    floatx4 hacc = (floatx4){1.f, 1.f, 1.f, 1.f};   // c = w*16 + q*4 + i, b = m

    // h ds_write target: value (b=m, a=c=w*16+q*4+i) -> B-frag kt=w>>1,
    // arel=(w&1)*16+q*4+i, lane' = m + 16*((w&1)*2+(q>>1)), dwords (q&1)*2 +{0,1}
    unsigned int* const bfw = (unsigned int*)&bfbuf[0][0][0];
    const int wr_dw = (w >> 1) * 256 + (m + 16 * ((w & 1) * 2 + (q >> 1))) * 4 + (q & 1) * 2;

    __syncthreads();

// PF: 1 -> prefetch W(NN+2); WAIT: vm_wait8 or vm_wait0
#define SITE_BODY(NN, PAR, WBUF, X0, X1, PF, WAIT) do {                             \
    lds_barrier();                                                                  \
    short8 bf0 = bfbuf[PAR][0][l];                                                  \
    short8 bf1 = bfbuf[PAR][1][l];                                                  \
    short8 bf2 = bfbuf[PAR][2][l];                                                  \
    short8 bf3 = bfbuf[PAR][3][l];                                                  \
    WAIT();                                                                         \
    floatx4 z = (floatx4){0.f, 0.f, 0.f, 0.f};                                      \
    floatx4 p0 = __builtin_amdgcn_mfma_f32_16x16x32_bf16(WBUF[0], bf0, z, 0, 0, 0); \
    floatx4 p1 = __builtin_amdgcn_mfma_f32_16x16x32_bf16(WBUF[2], bf2, z, 0, 0, 0); \
    floatx4 q0 = __builtin_amdgcn_mfma_f32_16x16x32_bf16(WBUF[4], bf0, z, 0, 0, 0); \
    floatx4 q1 = __builtin_amdgcn_mfma_f32_16x16x32_bf16(WBUF[6], bf2, z, 0, 0, 0); \
    p0 = __builtin_amdgcn_mfma_f32_16x16x32_bf16(WBUF[1], bf1, p0, 0, 0, 0);        \
    p1 = __builtin_amdgcn_mfma_f32_16x16x32_bf16(WBUF[3], bf3, p1, 0, 0, 0);        \
    q0 = __builtin_amdgcn_mfma_f32_16x16x32_bf16(WBUF[5], bf1, q0, 0, 0, 0);        \
    q1 = __builtin_amdgcn_mfma_f32_16x16x32_bf16(WBUF[7], bf3, q1, 0, 0, 0);        \
    if (PF) {                                                                       \
        const char* pb_ = wsb + (size_t)((NN) + 2) * 65536;                         \
        WBUF[0] = gload<0>(pb_);        WBUF[1] = gload<1024>(pb_);                 \
        WBUF[2] = gload<2048>(pb_);     WBUF[3] = gload<3072>(pb_);                 \
        const char* pc_ = pb_ + 4096;                                               \
        WBUF[4] = gload<0>(pc_);        WBUF[5] = gload<1024>(pc_);                 \
        WBUF[6] = gload<2048>(pc_);     WBUF[7] = gload<3072>(pc_);                 \
    }                                                                               \
    _Pragma("unroll")                                                               \
    for (int i = 0; i < 4; i++)                                                     \
        hacc[i] += (X0) * (p0[i] + p1[i]) + (X1) * (q0[i] + q1[i]);                 \
    uint2 pk;                                                                       \
    pk.x = cvt_pk_bf16(hacc[0], hacc[1]);                                           \
    pk.y = cvt_pk_bf16(hacc[2], hacc[3]);                                           \
    *(uint2*)&bfw[((PAR) ^ 1) * 1024 + wr_dw] = pk;                                 \
} while (0)

    // main loop: sites 0..767 (nb <= 752) — all guards compile-time true
    for (int nb = 0; nb < LL - 16; nb += 16) {
        xB0 = gloadf4(xp0 + nb + 8);
        xB1 = gloadf4(xp0 + nb + 12);
        xB2 = gloadf4(xp1 + nb + 8);
        xB3 = gloadf4(xp1 + nb + 12);
        SITE_BODY(nb + 0,  0, bWA, xA0[0], xA2[0], 1, vm_wait8);
        SITE_BODY(nb + 1,  1, bWB, xA0[1], xA2[1], 1, vm_wait8);
        SITE_BODY(nb + 2,  0, bWA, xA0[2], xA2[2], 1, vm_wait8);
        SITE_BODY(nb + 3,  1, bWB, xA0[3], xA2[3], 1, vm_wait8);
        SITE_BODY(nb + 4,  0, bWA, xA1[0], xA3[0], 1, vm_wait8);
        SITE_BODY(nb + 5,  1, bWB, xA1[1], xA3[1], 1, vm_wait8);
        SITE_BODY(nb + 6,  0, bWA, xA1[2], xA3[2], 1, vm_wait8);
        SITE_BODY(nb + 7,  1, bWB, xA1[3], xA3[3], 1, vm_wait8);
        xA0 = gloadf4(xp0 + nb + 16);
        xA1 = gloadf4(xp0 + nb + 20);
        xA2 = gloadf4(xp1 + nb + 16);
        xA3 = gloadf4(xp1 + nb + 20);
        SITE_BODY(nb + 8,  0, bWA, xB0[0], xB2[0], 1, vm_wait8);
        SITE_BODY(nb + 9,  1, bWB, xB0[1], xB2[1], 1, vm_wait8);
        SITE_BODY(nb + 10, 0, bWA, xB0[2], xB2[2], 1, vm_wait8);
        SITE_BODY(nb + 11, 1, bWB, xB0[3], xB2[3], 1, vm_wait8);
        SITE_BODY(nb + 12, 0, bWA, xB1[0], xB3[0], 1, vm_wait8);
        SITE_BODY(nb + 13, 1, bWB, xB1[1], xB3[1], 1, vm_wait8);
        SITE_BODY(nb + 14, 0, bWA, xB1[2], xB3[2], 1, vm_wait8);
        SITE_BODY(nb + 15, 1, bWB, xB1[3], xB3[3], 1, vm_wait8);
    }

    // peeled tail: sites 768..783 (literal indices; prefetch guard folds)
    xB0 = gloadf4(xp0 + 768 + 8);
    xB1 = gloadf4(xp0 + 768 + 12);
    xB2 = gloadf4(xp1 + 768 + 8);
    xB3 = gloadf4(xp1 + 768 + 12);
    SITE_BODY(768, 0, bWA, xA0[0], xA2[0], 1, vm_wait8);
    SITE_BODY(769, 1, bWB, xA0[1], xA2[1], 1, vm_wait8);
    SITE_BODY(770, 0, bWA, xA0[2], xA2[2], 1, vm_wait8);
    SITE_BODY(771, 1, bWB, xA0[3], xA2[3], 1, vm_wait8);
    SITE_BODY(772, 0, bWA, xA1[0], xA3[0], 1, vm_wait8);
    SITE_BODY(773, 1, bWB, xA1[1], xA3[1], 1, vm_wait8);
    SITE_BODY(774, 0, bWA, xA1[2], xA3[2], 1, vm_wait8);
    SITE_BODY(775, 1, bWB, xA1[3], xA3[3], 1, vm_wait8);
    SITE_BODY(776, 0, bWA, xB0[0], xB2[0], 1, vm_wait8);
    SITE_BODY(777, 1, bWB, xB0[1], xB2[1], 1, vm_wait8);
    SITE_BODY(778, 0, bWA, xB0[2], xB2[2], 1, vm_wait8);
    SITE_BODY(779, 1, bWB, xB0[3], xB2[3], 1, vm_wait8);
    SITE_BODY(780, 0, bWA, xB1[0], xB3[0], 1, vm_wait8);
    SITE_BODY(781, 1, bWB, xB1[1], xB3[1], 1, vm_wait8);
    SITE_BODY(782, 0, bWA, xB1[2], xB3[2], 0, vm_wait8);
    SITE_BODY(783, 1, bWB, xB1[3], xB3[3], 0, vm_wait0);
#undef SITE_BODY

    // hacc (exact fp32) -> LDS, then logits = h @ V
    *(floatx4*)&hfin[m * 136 + w * 16 + q * 4] = hacc;
    __syncthreads();

    if (t < BC * CLS) {
        int r = t / CLS, cls = t % CLS;
        float sum = 0.f;
        for (int a = 0; a < CHI; a++) sum += hfin[r * 136 + a] * V[a * CLS + cls];
        out[(size_t)(rb + r) * CLS + cls] = sum;
    }
}

extern "C" void kernel_launch(void* const* d_in, const int* in_sizes, int n_in,
                              void* d_out, int out_size, void* d_ws, size_t ws_size,
                              hipStream_t stream) {
    const float* x = (const float*)d_in[0];
    const float* W = (const float*)d_in[1];
    const float* V = (const float*)d_in[2];
    float* out = (float*)d_out;

    prep_kernel<<<LL * 8, 256, 0, stream>>>(W, (uint4*)d_ws);
    mps_kernel<<<NBLK, 512, 0, stream>>>(x, (const unsigned short*)d_ws, V, out);
}

// Round 4
// 682.516 us; speedup vs baseline: 1.0057x; 1.0029x over previous
//
#include <hip/hip_runtime.h>

#define LL 784
#define CHI 128
#define CLS 10
#define BC 16
#define NBLK 64          // 1024/16

typedef __attribute__((ext_vector_type(8))) short short8;
typedef __attribute__((ext_vector_type(4))) float floatx4;

__device__ inline unsigned int f2bf(float v) {
    unsigned int u = __float_as_uint(v);
    u += 0x7fffu + ((u >> 16) & 1u);   // RNE
    return u >> 16;
}

// workgroup barrier that does NOT drain vmcnt — keeps W prefetch in flight.
__device__ inline void lds_barrier() {
    asm volatile("s_waitcnt lgkmcnt(0)\n\ts_barrier" ::: "memory");
}

// packed fp32x2 -> bf16x2 (RNE), lo = first arg
__device__ inline unsigned int cvt_pk_bf16(float lo, float hi) {
    unsigned int r;
    asm("v_cvt_pk_bf16_f32 %0, %1, %2" : "=v"(r) : "v"(lo), "v"(hi));
    return r;
}

// un-sinkable 16B global load: volatile asm pins the ISSUE position.
template <int OFF>
__device__ inline short8 gload(const char* p) {
    short8 r;
    asm volatile("global_load_dwordx4 %0, %1, off offset:%2"
                 : "=v"(r) : "v"(p), "i"(OFF));
    return r;
}

__device__ inline floatx4 gloadf4(const float* p) {
    floatx4 r;
    asm volatile("global_load_dwordx4 %0, %1, off"
                 : "=v"(r) : "v"(p));
    return r;
}

// counted waits. sched_barrier stops MFMA hoisting above the wait (rule #18).
// FIFO invariant (4-deep pipeline): at site n's wait, batches W(n+1..n+3)
// (24 loads) + x strays have been issued since W(n) -> vmcnt(24) guarantees
// W(n) retired while keeping 3 future batches in flight.
__device__ inline void vm_wait24() {
    asm volatile("s_waitcnt vmcnt(24)" ::: "memory");
    __builtin_amdgcn_sched_barrier(0);
}
__device__ inline void vm_wait16() {
    asm volatile("s_waitcnt vmcnt(16)" ::: "memory");
    __builtin_amdgcn_sched_barrier(0);
}
__device__ inline void vm_wait8() {
    asm volatile("s_waitcnt vmcnt(8)" ::: "memory");
    __builtin_amdgcn_sched_barrier(0);
}
__device__ inline void vm_wait0() {
    asm volatile("s_waitcnt vmcnt(0)" ::: "memory");
    __builtin_amdgcn_sched_barrier(0);
}

// ---------------------------------------------------------------------------
// prep: W fp32 (L,2,CHI,CHI) -> bf16 MFMA fragments via LDS transpose.
// UNCHANGED (layout verified by passing rounds).
// ws uint4 index: (((n*8 + nt)*2 + s)*4 + kt)*64 + l
//   lane l elem j: value = W[n][s][a = kt*32 + (l>>4)*8 + j][c = nt*16 + (l&15)]
// ---------------------------------------------------------------------------
__global__ __launch_bounds__(256) void prep_kernel(const float* __restrict__ W,
                                                   uint4* __restrict__ ws4) {
    __shared__ float tile[32 * 132];
    const int b = blockIdx.x;            // n*8 + s*4 + kt
    const int n = b >> 3, s = (b >> 2) & 1, kt = b & 3;
    const float* Wp = W + ((size_t)(n * 2 + s) * CHI + kt * 32) * CHI;
    const int t = threadIdx.x;
    #pragma unroll
    for (int k = 0; k < 4; k++) {
        int v = t + k * 256;             // 0..1023 float4s
        int a = v >> 5, c4 = v & 31;
        float4 val = *(const float4*)(Wp + a * CHI + c4 * 4);
        *(float4*)&tile[a * 132 + c4 * 4] = val;
    }
    __syncthreads();
    const int l = t & 63, f0 = t >> 6;
    const int m_ = l & 15, q_ = l >> 4;
    #pragma unroll
    for (int ff = 0; ff < 2; ff++) {
        int nt = f0 + ff * 4;
        const float* tp = &tile[(q_ * 8) * 132 + nt * 16 + m_];
        uint4 pk;
        pk.x = f2bf(tp[0 * 132]) | (f2bf(tp[1 * 132]) << 16);
        pk.y = f2bf(tp[2 * 132]) | (f2bf(tp[3 * 132]) << 16);
        pk.z = f2bf(tp[4 * 132]) | (f2bf(tp[5 * 132]) << 16);
        pk.w = f2bf(tp[6 * 132]) | (f2bf(tp[7 * 132]) << 16);
        ws4[(size_t)(((n * 8 + nt) * 2 + s) * 4 + kt) * 64 + l] = pk;
    }
}

// ---------------------------------------------------------------------------
// main: 64 blocks x 512 threads (8 waves). Wave w owns c-tile nt=w.
// Transposed compute D[c][b] = sum_a W[a][c] h[b][a]; A-frags = ws, B-frags =
// bf16 h in LDS ping-pong (1 lgkm barrier/site). W: 8 frags/site/wave,
// 4-site-deep register pipeline (bWA..bWD, 128 VGPRs), volatile-asm loads;
// per-site vmcnt(24) keeps 3 future batches (24 loads, 24KB/wave) permanently
// in flight -> vmem queue is decoupled from the barrier-paced site loop.
// Last 16 sites peeled: waits drain 24 -> 24 -> 16 -> 8 -> 0.
// ---------------------------------------------------------------------------
__global__ __launch_bounds__(512) void mps_kernel(const float* __restrict__ x,
                                                  const unsigned short* __restrict__ ws,
                                                  const float* __restrict__ V,
                                                  float* __restrict__ out) {
    __shared__ short8 bfbuf[2][4][64];   // [par][kt][lane] B-frags of h^T, 8 KB
    __shared__ float hfin[BC * 136];     // final h for h@V

    const int t = threadIdx.x;
    const int w = t >> 6, l = t & 63;
    const int m = l & 15, q = l >> 4;
    const int rb = blockIdx.x * BC;

    // init bfbuf[0] = bf16(1.0)  (1024 uints, 512 threads -> 2 each)
    for (int i = t; i < 1024; i += 512)
        ((unsigned int*)&bfbuf[0][0][0])[i] = 0x3F803F80u;

    // ---- x: per-lane registers, batch row b = m ----
    const float* xp0 = x + (size_t)(rb + m) * (2 * LL);   // s = 0
    const float* xp1 = xp0 + LL;                          // s = 1
    floatx4 xA0, xA1, xA2, xA3, xB0, xB1, xB2, xB3;
    xA0 = gloadf4(xp0 + 0);  xA1 = gloadf4(xp0 + 4);
    xA2 = gloadf4(xp1 + 0);  xA3 = gloadf4(xp1 + 4);

    // ---- W: wave-private byte base; frag f=s*4+kt at +f*1024, site at +n*65536
    const char* wsb = (const char*)ws + (size_t)w * 8192 + (size_t)l * 16;

    short8 bWA[8], bWB[8], bWC[8], bWD[8];
#define LOAD_BATCH(BUF, PTR) do {                                   \
    const char* p_ = (PTR);                                         \
    BUF[0] = gload<0>(p_);           BUF[1] = gload<1024>(p_);      \
    BUF[2] = gload<2048>(p_);        BUF[3] = gload<3072>(p_);      \
    BUF[4] = gload<0>(p_ + 4096);    BUF[5] = gload<1024>(p_ + 4096); \
    BUF[6] = gload<2048>(p_ + 4096); BUF[7] = gload<3072>(p_ + 4096); \
} while (0)

    LOAD_BATCH(bWA, wsb);
    LOAD_BATCH(bWB, wsb + 1 * 65536);
    LOAD_BATCH(bWC, wsb + 2 * 65536);
    LOAD_BATCH(bWD, wsb + 3 * 65536);

    floatx4 hacc = (floatx4){1.f, 1.f, 1.f, 1.f};   // c = w*16 + q*4 + i, b = m

    // h ds_write target (verified mapping): value (b=m, a=w*16+q*4+i) ->
    // B-frag kt=w>>1, lane' = m + 16*((w&1)*2+(q>>1)), dwords (q&1)*2 + {0,1}
    unsigned int* const bfw = (unsigned int*)&bfbuf[0][0][0];
    const int wr_dw = (w >> 1) * 256 + (m + 16 * ((w & 1) * 2 + (q >> 1))) * 4 + (q & 1) * 2;

    __syncthreads();

// PF: 1 -> prefetch W(NN+4) into WBUF; WAIT: one of the vm_wait*
#define SITE_BODY(NN, PAR, WBUF, X0, X1, PF, WAIT) do {                             \
    lds_barrier();                                                                  \
    short8 bf0 = bfbuf[PAR][0][l];                                                  \
    short8 bf1 = bfbuf[PAR][1][l];                                                  \
    short8 bf2 = bfbuf[PAR][2][l];                                                  \
    short8 bf3 = bfbuf[PAR][3][l];                                                  \
    WAIT();                                                                         \
    floatx4 z = (floatx4){0.f, 0.f, 0.f, 0.f};                                      \
    floatx4 p0 = __builtin_amdgcn_mfma_f32_16x16x32_bf16(WBUF[0], bf0, z, 0, 0, 0); \
    floatx4 p1 = __builtin_amdgcn_mfma_f32_16x16x32_bf16(WBUF[2], bf2, z, 0, 0, 0); \
    floatx4 q0 = __builtin_amdgcn_mfma_f32_16x16x32_bf16(WBUF[4], bf0, z, 0, 0, 0); \
    floatx4 q1 = __builtin_amdgcn_mfma_f32_16x16x32_bf16(WBUF[6], bf2, z, 0, 0, 0); \
    p0 = __builtin_amdgcn_mfma_f32_16x16x32_bf16(WBUF[1], bf1, p0, 0, 0, 0);        \
    p1 = __builtin_amdgcn_mfma_f32_16x16x32_bf16(WBUF[3], bf3, p1, 0, 0, 0);        \
    q0 = __builtin_amdgcn_mfma_f32_16x16x32_bf16(WBUF[5], bf1, q0, 0, 0, 0);        \
    q1 = __builtin_amdgcn_mfma_f32_16x16x32_bf16(WBUF[7], bf3, q1, 0, 0, 0);        \
    if (PF) LOAD_BATCH(WBUF, wsb + (size_t)((NN) + 4) * 65536);                     \
    _Pragma("unroll")                                                               \
    for (int i = 0; i < 4; i++)                                                     \
        hacc[i] += (X0) * (p0[i] + p1[i]) + (X1) * (q0[i] + q1[i]);                 \
    uint2 pk;                                                                       \
    pk.x = cvt_pk_bf16(hacc[0], hacc[1]);                                           \
    pk.y = cvt_pk_bf16(hacc[2], hacc[3]);                                           \
    *(uint2*)&bfw[((PAR) ^ 1) * 1024 + wr_dw] = pk;                                 \
} while (0)

    // main loop: sites 0..767 — steady state, vmcnt(24), always prefetch
    for (int nb = 0; nb < LL - 16; nb += 16) {
        xB0 = gloadf4(xp0 + nb + 8);
        xB1 = gloadf4(xp0 + nb + 12);
        xB2 = gloadf4(xp1 + nb + 8);
        xB3 = gloadf4(xp1 + nb + 12);
        SITE_BODY(nb + 0,  0, bWA, xA0[0], xA2[0], 1, vm_wait24);
        SITE_BODY(nb + 1,  1, bWB, xA0[1], xA2[1], 1, vm_wait24);
        SITE_BODY(nb + 2,  0, bWC, xA0[2], xA2[2], 1, vm_wait24);
        SITE_BODY(nb + 3,  1, bWD, xA0[3], xA2[3], 1, vm_wait24);
        SITE_BODY(nb + 4,  0, bWA, xA1[0], xA3[0], 1, vm_wait24);
        SITE_BODY(nb + 5,  1, bWB, xA1[1], xA3[1], 1, vm_wait24);
        SITE_BODY(nb + 6,  0, bWC, xA1[2], xA3[2], 1, vm_wait24);
        SITE_BODY(nb + 7,  1, bWD, xA1[3], xA3[3], 1, vm_wait24);
        xA0 = gloadf4(xp0 + nb + 16);
        xA1 = gloadf4(xp0 + nb + 20);
        xA2 = gloadf4(xp1 + nb + 16);
        xA3 = gloadf4(xp1 + nb + 20);
        SITE_BODY(nb + 8,  0, bWA, xB0[0], xB2[0], 1, vm_wait24);
        SITE_BODY(nb + 9,  1, bWB, xB0[1], xB2[1], 1, vm_wait24);
        SITE_BODY(nb + 10, 0, bWC, xB0[2], xB2[2], 1, vm_wait24);
        SITE_BODY(nb + 11, 1, bWD, xB0[3], xB2[3], 1, vm_wait24);
        SITE_BODY(nb + 12, 0, bWA, xB1[0], xB3[0], 1, vm_wait24);
        SITE_BODY(nb + 13, 1, bWB, xB1[1], xB3[1], 1, vm_wait24);
        SITE_BODY(nb + 14, 0, bWC, xB1[2], xB3[2], 1, vm_wait24);
        SITE_BODY(nb + 15, 1, bWD, xB1[3], xB3[3], 1, vm_wait24);
    }

    // peeled tail: sites 768..783. PF while NN+4 <= 783; waits drain 24->16->8->0.
    xB0 = gloadf4(xp0 + 768 + 8);
    xB1 = gloadf4(xp0 + 768 + 12);
    xB2 = gloadf4(xp1 + 768 + 8);
    xB3 = gloadf4(xp1 + 768 + 12);
    SITE_BODY(768, 0, bWA, xA0[0], xA2[0], 1, vm_wait24);   // PF 772
    SITE_BODY(769, 1, bWB, xA0[1], xA2[1], 1, vm_wait24);   // PF 773
    SITE_BODY(770, 0, bWC, xA0[2], xA2[2], 1, vm_wait24);   // PF 774
    SITE_BODY(771, 1, bWD, xA0[3], xA2[3], 1, vm_wait24);   // PF 775
    SITE_BODY(772, 0, bWA, xA1[0], xA3[0], 1, vm_wait24);   // PF 776
    SITE_BODY(773, 1, bWB, xA1[1], xA3[1], 1, vm_wait24);   // PF 777
    SITE_BODY(774, 0, bWC, xA1[2], xA3[2], 1, vm_wait24);   // PF 778
    SITE_BODY(775, 1, bWD, xA1[3], xA3[3], 1, vm_wait24);   // PF 779
    SITE_BODY(776, 0, bWA, xB0[0], xB2[0], 1, vm_wait24);   // PF 780
    SITE_BODY(777, 1, bWB, xB0[1], xB2[1], 1, vm_wait24);   // PF 781
    SITE_BODY(778, 0, bWC, xB0[2], xB2[2], 1, vm_wait24);   // PF 782
    SITE_BODY(779, 1, bWD, xB0[3], xB2[3], 1, vm_wait24);   // PF 783
    SITE_BODY(780, 0, bWA, xB1[0], xB3[0], 0, vm_wait24);   // 781..783 in flight
    SITE_BODY(781, 1, bWB, xB1[1], xB3[1], 0, vm_wait16);
    SITE_BODY(782, 0, bWC, xB1[2], xB3[2], 0, vm_wait8);
    SITE_BODY(783, 1, bWD, xB1[3], xB3[3], 0, vm_wait0);
#undef SITE_BODY
#undef LOAD_BATCH

    // hacc (exact fp32) -> LDS, then logits = h @ V
    *(floatx4*)&hfin[m * 136 + w * 16 + q * 4] = hacc;
    __syncthreads();

    if (t < BC * CLS) {
        int r = t / CLS, cls = t % CLS;
        float sum = 0.f;
        for (int a = 0; a < CHI; a++) sum += hfin[r * 136 + a] * V[a * CLS + cls];
        out[(size_t)(rb + r) * CLS + cls] = sum;
    }
}

extern "C" void kernel_launch(void* const* d_in, const int* in_sizes, int n_in,
                              void* d_out, int out_size, void* d_ws, size_t ws_size,
                              hipStream_t stream) {
    const float* x = (const float*)d_in[0];
    const float* W = (const float*)d_in[1];
    const float* V = (const float*)d_in[2];
    float* out = (float*)d_out;

    prep_kernel<<<LL * 8, 256, 0, stream>>>(W, (uint4*)d_ws);
    mps_kernel<<<NBLK, 512, 0, stream>>>(x, (const unsigned short*)d_ws, V, out);
}